// Round 10
// baseline (563.007 us; speedup 1.0000x reference)
//
#include <hip/hip_runtime.h>
#include <hip/hip_bf16.h>

#define NN 100000
#define EE 1600000
#define DH 128
#define DOUT 40
#define BN_EPS 1e-5f

typedef unsigned int uint;
typedef unsigned short ushort;
typedef __attribute__((ext_vector_type(8))) short bf16x8;
typedef __attribute__((ext_vector_type(4))) float f32x4;

#define NB 196     // ceil(NN/512) buckets of 512 nodes
#define NPB 196    // partition/hist blocks: ceil(EE/PEB)
#define PEB 8192   // edges per partition block
#define ABB 2048   // bnapply grid-stride blocks
#define NFB 72     // k_front cast/zero blocks
#define G64 1563   // (NN+63)/64 row-tile blocks

__device__ __forceinline__ float b2f(uint u) { return __uint_as_float(u << 16); }
__device__ __forceinline__ ushort f2b(float f) {
  __hip_bfloat16 b = __float2bfloat16(f);
  return *reinterpret_cast<ushort*>(&b);
}
__device__ __forceinline__ uint2 cast4(float4 v) {
  uint2 o;
  o.x = (uint)f2b(v.x) | ((uint)f2b(v.y) << 16);
  o.y = (uint)f2b(v.z) | ((uint)f2b(v.w) << 16);
  return o;
}
__device__ __forceinline__ bf16x8 frag_f32(const float* p) {
  uint2 a = cast4(*(const float4*)p);
  uint2 b = cast4(*(const float4*)(p + 4));
  union { uint u[4]; bf16x8 v; } r;
  r.u[0] = a.x; r.u[1] = a.y; r.u[2] = b.x; r.u[3] = b.y;
  return r.v;
}

// ---------------- k_front: weight casts + zero region + bucket histograms ----------------
#define N4FC  4096      // 128*128/4
#define N4CV  12288     // 3*128*128/4
#define N4CLS 1280      // 40*128/4
#define NZ2   610       // (1024 sums + 196 gfill) / 2 uint2 zeros
__global__ __launch_bounds__(256) void k_front(const float4* __restrict__ w1s, uint2* __restrict__ w1d,
                                               const float4* __restrict__ w2s, uint2* __restrict__ w2d,
                                               const float4* __restrict__ w3s, uint2* __restrict__ w3d,
                                               uint2* __restrict__ zp,
                                               const int* __restrict__ col, int* __restrict__ hist_mat) {
  __shared__ int lh[NB];
  if (blockIdx.x < NFB) {
    int i = blockIdx.x * 256 + threadIdx.x;
    if (i < N4FC) { w1d[i] = cast4(w1s[i]); return; }
    i -= N4FC;
    if (i < N4CV) { w2d[i] = cast4(w2s[i]); return; }
    i -= N4CV;
    if (i < N4CLS) { w3d[i] = cast4(w3s[i]); return; }
    i -= N4CLS;
    if (i < NZ2) zp[i] = make_uint2(0, 0);
    return;
  }
  int hb = blockIdx.x - NFB;
  int tid = threadIdx.x;
  for (int i = tid; i < NB; i += 256) lh[i] = 0;
  __syncthreads();
  int base = hb * PEB;
#pragma unroll
  for (int i = 0; i < 32; ++i) {
    int e = base + i * 256 + tid;
    if (e < EE) atomicAdd(&lh[col[e] >> 9], 1);
  }
  __syncthreads();
  for (int i = tid; i < NB; i += 256) hist_mat[hb * NB + i] = lh[i];
}

// ---------------- k_pg0: partition (with self-bscan) ∪ layer-0 GEMM ----------------
__global__ __launch_bounds__(256) void k_pg0(const int* __restrict__ row, const int* __restrict__ col,
                                             const int* __restrict__ hist_mat, int* __restrict__ gfill,
                                             uint* __restrict__ pairbuf, int* __restrict__ bbase,
                                             const float* __restrict__ A, const ushort* __restrict__ W,
                                             const float* __restrict__ bias, ushort* __restrict__ Y,
                                             float* __restrict__ sums, int n) {
  __shared__ int smu[1024];
  int t = threadIdx.x;
  if (blockIdx.x < NPB) {
    // ---------- partition block ----------
    int* lhist = smu;          // [196]
    int* lbase = smu + 196;    // [196]
    int* lgoff = smu + 392;    // [196]
    int* sm    = smu + 588;    // [256]
    // self-bscan: column-sum + scan of hist_mat
    int tot = 0;
    if (t < NB)
      for (int i = 0; i < NPB; ++i) tot += hist_mat[i * NB + t];
    sm[t] = tot;
    __syncthreads();
    for (int off = 1; off < 256; off <<= 1) {
      int v = (t >= off) ? sm[t - off] : 0;
      __syncthreads();
      sm[t] += v;
      __syncthreads();
    }
    if (t < NB) lbase[t] = sm[t] - tot;  // exclusive prefix
    if (blockIdx.x == 0) {
      if (t < NB) bbase[t] = sm[t] - tot;
      if (t == NB - 1) bbase[NB] = sm[t];
    }
    for (int i = t; i < NB; i += 256) lhist[i] = 0;
    __syncthreads();
    // histogram this block's edges
    int base = blockIdx.x * PEB;
    int packed[32];
#pragma unroll
    for (int i = 0; i < 32; ++i) {
      int e = base + i * 256 + t;
      packed[i] = -1;
      if (e < EE) {
        int c = col[e];
        int b = c >> 9, loc = c & 511;
        int p = atomicAdd(&lhist[b], 1);
        packed[i] = (b << 22) | (loc << 13) | p;
      }
    }
    __syncthreads();
    for (int i = t; i < NB; i += 256) lgoff[i] = atomicAdd(&gfill[i], lhist[i]);
    __syncthreads();
#pragma unroll
    for (int i = 0; i < 32; ++i) {
      if (packed[i] >= 0) {
        int e = base + i * 256 + t;
        int b = packed[i] >> 22, loc = (packed[i] >> 13) & 511, p = packed[i] & 8191;
        pairbuf[(size_t)lbase[b] + lgoff[b] + p] = ((uint)loc << 17) | (uint)row[e];
      }
    }
    return;
  }
  // ---------- layer-0 GEMM block (fp32 A, direct fragments) ----------
  float* ls1 = (float*)smu;        // [4][128]
  float* ls2 = (float*)smu + 512;
  int bid = blockIdx.x - NPB;
  int w = t >> 6, l = t & 63;
  int quad = l >> 4, m = l & 15;
  int r0 = bid * 128;
  bf16x8 af[2][4];
#pragma unroll
  for (int rt = 0; rt < 2; ++rt) {
    int ar = min(r0 + w * 32 + rt * 16 + m, n - 1);
#pragma unroll
    for (int ks = 0; ks < 4; ++ks)
      af[rt][ks] = frag_f32(A + (size_t)ar * 128 + ks * 32 + quad * 8);
  }
#pragma unroll
  for (int ct = 0; ct < 8; ++ct) {
    int c = ct * 16 + m;
    bf16x8 bfr[4];
#pragma unroll
    for (int ks = 0; ks < 4; ++ks)
      bfr[ks] = *(const bf16x8*)&W[(size_t)c * 128 + ks * 32 + quad * 8];
    float b = bias[c];
    float s1 = 0.f, s2 = 0.f;
#pragma unroll
    for (int rt = 0; rt < 2; ++rt) {
      f32x4 acc = {0.f, 0.f, 0.f, 0.f};
#pragma unroll
      for (int ks = 0; ks < 4; ++ks)
        acc = __builtin_amdgcn_mfma_f32_16x16x32_bf16(af[rt][ks], bfr[ks], acc, 0, 0, 0);
      int rbase = r0 + w * 32 + rt * 16 + quad * 4;
#pragma unroll
      for (int i2 = 0; i2 < 4; ++i2) {
        int r = rbase + i2;
        if (r < n) {
          float v = acc[i2] + b;
          s1 += v;
          s2 += v * v;
          Y[(size_t)r * 128 + c] = f2b(v);
        }
      }
    }
    s1 += __shfl_xor(s1, 16);
    s1 += __shfl_xor(s1, 32);
    s2 += __shfl_xor(s2, 16);
    s2 += __shfl_xor(s2, 32);
    if (quad == 0) {
      ls1[w * 128 + c] = s1;
      ls2[w * 128 + c] = s2;
    }
  }
  __syncthreads();
  if (t < 128) {
    float a1 = ls1[t] + ls1[128 + t] + ls1[256 + t] + ls1[384 + t];
    float a2 = ls2[t] + ls2[128 + t] + ls2[256 + t] + ls2[384 + t];
    atomicAdd(&sums[t], a1);
    atomicAdd(&sums[128 + t], a2);
  }
}

// ---------------- BN helpers ----------------
__device__ __forceinline__ void bn_prologue(float* ssl, const float* __restrict__ sums,
                                            const float* __restrict__ gamma,
                                            const float* __restrict__ beta) {
  int t = threadIdx.x;
  if (t < 128) {
    float mu = sums[t] * (1.f / NN);
    float var = sums[128 + t] * (1.f / NN) - mu * mu;
    float sc = gamma[t] * rsqrtf(var + BN_EPS);
    ssl[t] = sc;
    ssl[128 + t] = beta[t] - mu * sc;
  }
  __syncthreads();
}

__device__ __forceinline__ uint2 bn_elem(uint2 u, float4 sc, float4 sh) {
  float o0 = fmaxf(fmaf(sc.x, b2f(u.x & 0xffffu), sh.x), 0.f);
  float o1 = fmaxf(fmaf(sc.y, b2f(u.x >> 16), sh.y), 0.f);
  float o2 = fmaxf(fmaf(sc.z, b2f(u.y & 0xffffu), sh.z), 0.f);
  float o3 = fmaxf(fmaf(sc.w, b2f(u.y >> 16), sh.w), 0.f);
  uint2 o;
  o.x = (uint)f2b(o0) | ((uint)f2b(o1) << 16);
  o.y = (uint)f2b(o2) | ((uint)f2b(o3) << 16);
  return o;
}

__device__ __forceinline__ uint2 bn_elem_res(uint2 u, uint2 r, float4 sc, float4 sh) {
  float o0 = fmaxf(fmaf(sc.x, b2f(u.x & 0xffffu), sh.x), 0.f) + b2f(r.x & 0xffffu);
  float o1 = fmaxf(fmaf(sc.y, b2f(u.x >> 16), sh.y), 0.f) + b2f(r.x >> 16);
  float o2 = fmaxf(fmaf(sc.z, b2f(u.y & 0xffffu), sh.z), 0.f) + b2f(r.y & 0xffffu);
  float o3 = fmaxf(fmaf(sc.w, b2f(u.y >> 16), sh.w), 0.f) + b2f(r.y >> 16);
  uint2 o;
  o.x = (uint)f2b(o0) | ((uint)f2b(o1) << 16);
  o.y = (uint)f2b(o2) | ((uint)f2b(o3) << 16);
  return o;
}

// ---------------- k_mid: place (deg+scan+rowptr+dinv+srcbuf per bucket) ∪ bnapply layer-0 ----------------
__global__ __launch_bounds__(256) void k_mid(const uint* __restrict__ pairbuf,
                                             const int* __restrict__ bbase,
                                             int* __restrict__ rowptr, float* __restrict__ dinv,
                                             int* __restrict__ srcbuf,
                                             const uint2* __restrict__ y, uint2* __restrict__ h,
                                             uint2* __restrict__ x0, const float* __restrict__ sums,
                                             const float* __restrict__ gamma,
                                             const float* __restrict__ beta) {
  __shared__ __align__(16) int smraw[13569];  // stage[12288] | dega[512] | lrp[513] | ssum[256]
  if (blockIdx.x < NB) {
    int* stage = smraw;
    int* dega = smraw + 12288;
    int* lrp = smraw + 12800;
    int* ssum = smraw + 13313;
    int tid = threadIdx.x;
    int b = blockIdx.x;
    int nstart = b << 9;
    int nloc = min(nstart + 512, NN) - nstart;
    int estart = bbase[b];
    int count = bbase[b + 1] - estart;
    dega[tid] = 0;
    dega[256 + tid] = 0;
    __syncthreads();
    for (int i = tid; i < count; i += 256) atomicAdd(&dega[pairbuf[(size_t)estart + i] >> 17], 1);
    __syncthreads();
    int d0 = dega[2 * tid], d1 = dega[2 * tid + 1];
    ssum[tid] = d0 + d1;
    __syncthreads();
    for (int off = 1; off < 256; off <<= 1) {
      int t2 = (tid >= off) ? ssum[tid - off] : 0;
      __syncthreads();
      ssum[tid] += t2;
      __syncthreads();
    }
    int incl = ssum[tid];
    int ex = incl - (d0 + d1);
    lrp[2 * tid] = ex;
    lrp[2 * tid + 1] = ex + d0;
    if (tid == 255) lrp[512] = incl;
    __syncthreads();
    for (int i = tid; i < nloc; i += 256) {
      rowptr[nstart + i] = estart + lrp[i];
      int dg = dega[i];
      dinv[nstart + i] = (dg > 0) ? rsqrtf((float)dg) : 0.f;
    }
    if (b == NB - 1 && tid == 0) rowptr[NN] = estart + count;
    __syncthreads();
    dega[tid] = 0;
    dega[256 + tid] = 0;
    __syncthreads();
    if (count <= 12288) {
      for (int i = tid; i < count; i += 256) {
        uint v = pairbuf[(size_t)estart + i];
        int loc = v >> 17;
        int p = atomicAdd(&dega[loc], 1);
        stage[lrp[loc] + p] = (int)(v & 0x1FFFFu);
      }
      __syncthreads();
      for (int i = tid; i < count; i += 256) srcbuf[estart + i] = stage[i];
    } else {
      for (int i = tid; i < count; i += 256) {
        uint v = pairbuf[(size_t)estart + i];
        int loc = v >> 17;
        int p = atomicAdd(&dega[loc], 1);
        srcbuf[estart + lrp[loc] + p] = (int)(v & 0x1FFFFu);
      }
    }
    return;
  }
  float* ssl = (float*)smraw;
  bn_prologue(ssl, sums, gamma, beta);
  const float4* ss4 = (const float4*)ssl;
  for (int i = (blockIdx.x - NB) * 256 + threadIdx.x; i < NN * 32; i += ABB * 256) {
    int j = i & 31;
    uint2 o = bn_elem(y[i], ss4[j], ss4[32 + j]);
    h[i] = o;
    x0[i] = o;
  }
}

// ---------------- bnapply (layers 1..2): h = relu(bn(y)) + x0 ----------------
__global__ __launch_bounds__(256) void k_bnapply(const uint2* __restrict__ y, uint2* __restrict__ h,
                                                 const uint2* __restrict__ res,
                                                 const float* __restrict__ sums,
                                                 const float* __restrict__ gamma,
                                                 const float* __restrict__ beta) {
  __shared__ __align__(16) float ssl[256];
  bn_prologue(ssl, sums, gamma, beta);
  const float4* ss4 = (const float4*)ssl;
  for (int i = blockIdx.x * 256 + threadIdx.x; i < NN * 32; i += ABB * 256) {
    int j = i & 31;
    h[i] = bn_elem_res(y[i], res[i], ss4[j], ss4[32 + j]);
  }
}

// ---------------- fused SPMM + GEMM: per 64-row block, gather agg rows to LDS, then MFMA ----------------
__device__ __forceinline__ void fmac8(float* acc, uint4 v, float wgt) {
  acc[0] = fmaf(wgt, b2f(v.x & 0xffffu), acc[0]);
  acc[1] = fmaf(wgt, b2f(v.x >> 16), acc[1]);
  acc[2] = fmaf(wgt, b2f(v.y & 0xffffu), acc[2]);
  acc[3] = fmaf(wgt, b2f(v.y >> 16), acc[3]);
  acc[4] = fmaf(wgt, b2f(v.z & 0xffffu), acc[4]);
  acc[5] = fmaf(wgt, b2f(v.z >> 16), acc[5]);
  acc[6] = fmaf(wgt, b2f(v.w & 0xffffu), acc[6]);
  acc[7] = fmaf(wgt, b2f(v.w >> 16), acc[7]);
}

__global__ __launch_bounds__(256) void k_spgemm(const uint4* __restrict__ h4,
                                                const int* __restrict__ rowptr,
                                                const int* __restrict__ srcbuf,
                                                const float* __restrict__ dinv,
                                                const ushort* __restrict__ W,
                                                const float* __restrict__ bias,
                                                ushort* __restrict__ Y,
                                                float* __restrict__ sums, int n) {
  __shared__ ushort As[64][136];
  __shared__ float ls1[4][128];
  __shared__ float ls2[4][128];
  int t = threadIdx.x;
  int w = t >> 6, l = t & 63;
  int quad = l >> 4, m = l & 15;  // gather: group=quad, lane-in-group=m
  int r0 = blockIdx.x * 64;
  // ---- gather: wave w produces agg rows w*16 + i (wave-local, no barrier) ----
  for (int i = 0; i < 16; ++i) {
    int node = r0 + w * 16 + i;
    float acc[8];
#pragma unroll
    for (int j = 0; j < 8; ++j) acc[j] = 0.f;
    if (node < n) {
      int e0 = rowptr[node], e1 = rowptr[node + 1];
      int eA = e0 + quad;
      int s0 = (eA < e1) ? srcbuf[eA] : -1;
      int s1 = (eA + 4 < e1) ? srcbuf[eA + 4] : -1;
      int s2 = (eA + 8 < e1) ? srcbuf[eA + 8] : -1;
      int s3 = (eA + 12 < e1) ? srcbuf[eA + 12] : -1;
      while (eA < e1) {
        int eN = eA + 16;
        int t0 = (eN < e1) ? srcbuf[eN] : -1;
        int t1 = (eN + 4 < e1) ? srcbuf[eN + 4] : -1;
        int t2 = (eN + 8 < e1) ? srcbuf[eN + 8] : -1;
        int t3 = (eN + 12 < e1) ? srcbuf[eN + 12] : -1;
        int a1 = (s1 >= 0) ? s1 : s0;
        int a2 = (s2 >= 0) ? s2 : s0;
        int a3 = (s3 >= 0) ? s3 : s0;
        float w0 = dinv[s0];
        uint4 v0 = h4[(size_t)s0 * 16 + m];
        float w1 = (s1 >= 0) ? dinv[a1] : 0.f;
        uint4 v1 = h4[(size_t)a1 * 16 + m];
        float w2 = (s2 >= 0) ? dinv[a2] : 0.f;
        uint4 v2 = h4[(size_t)a2 * 16 + m];
        float w3 = (s3 >= 0) ? dinv[a3] : 0.f;
        uint4 v3 = h4[(size_t)a3 * 16 + m];
        fmac8(acc, v0, w0);
        fmac8(acc, v1, w1);
        fmac8(acc, v2, w2);
        fmac8(acc, v3, w3);
        s0 = t0; s1 = t1; s2 = t2; s3 = t3;
        eA = eN;
      }
    }
#pragma unroll
    for (int j = 0; j < 8; ++j) {
      acc[j] += __shfl_xor(acc[j], 16);
      acc[j] += __shfl_xor(acc[j], 32);
    }
    if (quad == 0) {
      float dc = (node < n) ? dinv[node] : 0.f;
      uint4 o;
      o.x = (uint)f2b(acc[0] * dc) | ((uint)f2b(acc[1] * dc) << 16);
      o.y = (uint)f2b(acc[2] * dc) | ((uint)f2b(acc[3] * dc) << 16);
      o.z = (uint)f2b(acc[4] * dc) | ((uint)f2b(acc[5] * dc) << 16);
      o.w = (uint)f2b(acc[6] * dc) | ((uint)f2b(acc[7] * dc) << 16);
      *(uint4*)&As[w * 16 + i][m * 8] = o;
    }
  }
  // ---- MFMA on own rows (written by this wave only) ----
  bf16x8 af[4];
#pragma unroll
  for (int ks = 0; ks < 4; ++ks)
    af[ks] = *(const bf16x8*)&As[w * 16 + m][ks * 32 + quad * 8];
#pragma unroll
  for (int ct = 0; ct < 8; ++ct) {
    int c = ct * 16 + m;
    bf16x8 bfr[4];
#pragma unroll
    for (int ks = 0; ks < 4; ++ks)
      bfr[ks] = *(const bf16x8*)&W[(size_t)c * 128 + ks * 32 + quad * 8];
    float b = bias[c];
    f32x4 acc2 = {0.f, 0.f, 0.f, 0.f};
#pragma unroll
    for (int ks = 0; ks < 4; ++ks)
      acc2 = __builtin_amdgcn_mfma_f32_16x16x32_bf16(af[ks], bfr[ks], acc2, 0, 0, 0);
    float s1 = 0.f, s2 = 0.f;
    int rbase = r0 + w * 16 + quad * 4;
#pragma unroll
    for (int i2 = 0; i2 < 4; ++i2) {
      int r = rbase + i2;
      if (r < n) {
        float v = acc2[i2] + b;
        s1 += v;
        s2 += v * v;
        Y[(size_t)r * 128 + c] = f2b(v);
      }
    }
    s1 += __shfl_xor(s1, 16);
    s1 += __shfl_xor(s1, 32);
    s2 += __shfl_xor(s2, 16);
    s2 += __shfl_xor(s2, 32);
    if (quad == 0) {
      ls1[w][c] = s1;
      ls2[w][c] = s2;
    }
  }
  __syncthreads();
  if (t < 128) {
    float a1 = ls1[0][t] + ls1[1][t] + ls1[2][t] + ls1[3][t];
    float a2 = ls2[0][t] + ls2[1][t] + ls2[2][t] + ls2[3][t];
    atomicAdd(&sums[t], a1);
    atomicAdd(&sums[128 + t], a2);
  }
}

// ---------------- fused bnapply layer-3 + classifier: h3 never materialized ----------------
__global__ __launch_bounds__(256) void k_bncls(const uint2* __restrict__ y, const uint2* __restrict__ x0,
                                               const float* __restrict__ sums,
                                               const float* __restrict__ gamma,
                                               const float* __restrict__ beta,
                                               const ushort* __restrict__ W,
                                               const float* __restrict__ bias,
                                               float* __restrict__ out, int n) {
  __shared__ ushort As[64][136];
  __shared__ __align__(16) float ssl[256];
  bn_prologue(ssl, sums, gamma, beta);
  const float4* ss4 = (const float4*)ssl;
  int t = threadIdx.x;
  int r0 = blockIdx.x * 64;
  for (int idx = t; idx < 64 * 32; idx += 256) {
    int r = idx >> 5, c2 = idx & 31;
    int gr = r0 + r;
    uint2 o = make_uint2(0, 0);
    if (gr < n)
      o = bn_elem_res(y[(size_t)gr * 32 + c2], x0[(size_t)gr * 32 + c2], ss4[c2], ss4[32 + c2]);
    *(uint2*)&As[r][c2 * 4] = o;
  }
  __syncthreads();
  int w = t >> 6, l = t & 63;
  int quad = l >> 4, m = l & 15;
  bf16x8 af[4];
#pragma unroll
  for (int ks = 0; ks < 4; ++ks)
    af[ks] = *(const bf16x8*)&As[w * 16 + m][ks * 32 + quad * 8];
#pragma unroll
  for (int ct = 0; ct < 3; ++ct) {
    int c = ct * 16 + m;
    int wr = min(c, DOUT - 1);
    bf16x8 bfr[4];
#pragma unroll
    for (int ks = 0; ks < 4; ++ks)
      bfr[ks] = *(const bf16x8*)&W[(size_t)wr * 128 + ks * 32 + quad * 8];
    f32x4 acc = {0.f, 0.f, 0.f, 0.f};
#pragma unroll
    for (int ks = 0; ks < 4; ++ks)
      acc = __builtin_amdgcn_mfma_f32_16x16x32_bf16(af[ks], bfr[ks], acc, 0, 0, 0);
    if (c < DOUT) {
      float b = bias[c];
      int rbase = r0 + w * 16 + quad * 4;
#pragma unroll
      for (int i = 0; i < 4; ++i) {
        int r = rbase + i;
        if (r < n) out[(size_t)r * DOUT + c] = acc[i] + b;
      }
    }
  }
}

// ---------------- launch ----------------
extern "C" void kernel_launch(void* const* d_in, const int* in_sizes, int n_in,
                              void* d_out, int out_size, void* d_ws, size_t ws_size,
                              hipStream_t stream) {
  const float* x      = (const float*)d_in[0];
  const int*   ei     = (const int*)d_in[1];
  const float* fc_w   = (const float*)d_in[2];
  const float* fc_b   = (const float*)d_in[3];
  const float* conv_w = (const float*)d_in[4];
  const float* conv_b = (const float*)d_in[5];
  const float* bn_g   = (const float*)d_in[6];
  const float* bn_b   = (const float*)d_in[7];
  const float* cls_w  = (const float*)d_in[8];
  const float* cls_b  = (const float*)d_in[9];
  const int* row  = ei;       // edge_index[0]
  const int* colv = ei + EE;  // edge_index[1]

  char* w = (char*)d_ws;
  auto alloc = [&](size_t bytes) {
    char* p = w;
    w += (bytes + 255) & ~(size_t)255;
    return p;
  };
  ushort* hb     = (ushort*)alloc((size_t)NN * 128 * 2);
  ushort* x0b    = (ushort*)alloc((size_t)NN * 128 * 2);
  ushort* yb     = (ushort*)alloc((size_t)NN * 128 * 2);
  ushort* wb_fc  = (ushort*)alloc(128 * 128 * 2);
  ushort* wb_cv  = (ushort*)alloc(3 * 128 * 128 * 2);
  ushort* wb_cls = (ushort*)alloc(DOUT * 128 * 2);
  int*   srcbuf  = (int*)alloc((size_t)EE * 4);
  uint*  pairbuf = (uint*)alloc((size_t)EE * 4);
  int*   hist_mat = (int*)alloc((size_t)NPB * NB * 4);
  int*   bbase   = (int*)alloc((NB + 1) * 4);
  int*   rowptr  = (int*)alloc((size_t)(NN + 1) * 4);
  float* dinv    = (float*)alloc((size_t)NN * 4);
  // contiguous zero region: sums(1024 floats) | gfill(196 ints)
  float* sums   = (float*)alloc(1024 * 4 + 196 * 4);
  int*   gfill  = (int*)(sums + 1024);

  // 1. front: weight casts + zeros + per-block bucket histograms
  k_front<<<NFB + NPB, 256, 0, stream>>>(
      (const float4*)fc_w, (uint2*)wb_fc, (const float4*)conv_w, (uint2*)wb_cv,
      (const float4*)cls_w, (uint2*)wb_cls, (uint2*)sums, colv, hist_mat);
  // 2. partition (self-bscan) ∪ layer-0 GEMM
  k_pg0<<<NPB + (NN + 127) / 128, 256, 0, stream>>>(row, colv, hist_mat, gfill, pairbuf, bbase,
                                                    x, wb_fc, fc_b, yb, sums + 0 * 256, NN);
  // 3. place ∪ bnapply0
  k_mid<<<NB + ABB, 256, 0, stream>>>(pairbuf, bbase, rowptr, dinv, srcbuf,
                                      (const uint2*)yb, (uint2*)hb, (uint2*)x0b,
                                      sums + 0 * 256, bn_g, bn_b);
  // 4-8. conv layers: fused spmm+gemm, then bnapply (layers 1-2) or fused bn+cls (layer 3)
  for (int i = 0; i < 3; ++i) {
    k_spgemm<<<G64, 256, 0, stream>>>((const uint4*)hb, rowptr, srcbuf, dinv,
                                      wb_cv + (size_t)i * 128 * 128, conv_b + (size_t)i * 128,
                                      yb, sums + (size_t)(i + 1) * 256, NN);
    if (i < 2)
      k_bnapply<<<ABB, 256, 0, stream>>>((const uint2*)yb, (uint2*)hb, (const uint2*)x0b,
                                         sums + (size_t)(i + 1) * 256,
                                         bn_g + (size_t)(i + 1) * 128, bn_b + (size_t)(i + 1) * 128);
  }
  // 9. final: bnapply3 ∪ classifier
  k_bncls<<<G64, 256, 0, stream>>>((const uint2*)yb, (const uint2*)x0b, sums + 3 * 256,
                                   bn_g + 3 * 128, bn_b + 3 * 128, wb_cls, cls_b, (float*)d_out, NN);
}

// Round 11
// 529.829 us; speedup vs baseline: 1.0626x; 1.0626x over previous
//
#include <hip/hip_runtime.h>
#include <hip/hip_bf16.h>

#define NN 100000
#define EE 1600000
#define DH 128
#define DOUT 40
#define BN_EPS 1e-5f

typedef unsigned int uint;
typedef unsigned short ushort;
typedef __attribute__((ext_vector_type(8))) short bf16x8;
typedef __attribute__((ext_vector_type(4))) float f32x4;

#define NB 196     // ceil(NN/512) buckets of 512 nodes
#define NPB 196    // partition/hist blocks: ceil(EE/PEB)
#define PEB 8192   // edges per partition block
#define ABB 2048   // bnapply grid-stride blocks
#define NFB 72     // k_front cast/zero blocks
#define G64 1563   // (NN+63)/64 row-tile blocks

__device__ __forceinline__ float b2f(uint u) { return __uint_as_float(u << 16); }
__device__ __forceinline__ ushort f2b(float f) {
  __hip_bfloat16 b = __float2bfloat16(f);
  return *reinterpret_cast<ushort*>(&b);
}
__device__ __forceinline__ uint2 cast4(float4 v) {
  uint2 o;
  o.x = (uint)f2b(v.x) | ((uint)f2b(v.y) << 16);
  o.y = (uint)f2b(v.z) | ((uint)f2b(v.w) << 16);
  return o;
}
__device__ __forceinline__ bf16x8 frag_f32(const float* p) {
  uint2 a = cast4(*(const float4*)p);
  uint2 b = cast4(*(const float4*)(p + 4));
  union { uint u[4]; bf16x8 v; } r;
  r.u[0] = a.x; r.u[1] = a.y; r.u[2] = b.x; r.u[3] = b.y;
  return r.v;
}

// ---------------- k_front: weight casts + zero region + bucket histograms ----------------
#define N4FC  4096      // 128*128/4
#define N4CV  12288     // 3*128*128/4
#define N4CLS 1280      // 40*128/4
#define NZ2   610       // (1024 sums + 196 gfill) / 2 uint2 zeros
__global__ __launch_bounds__(256) void k_front(const float4* __restrict__ w1s, uint2* __restrict__ w1d,
                                               const float4* __restrict__ w2s, uint2* __restrict__ w2d,
                                               const float4* __restrict__ w3s, uint2* __restrict__ w3d,
                                               uint2* __restrict__ zp,
                                               const int* __restrict__ col, int* __restrict__ hist_mat) {
  __shared__ int lh[NB];
  if (blockIdx.x < NFB) {
    int i = blockIdx.x * 256 + threadIdx.x;
    if (i < N4FC) { w1d[i] = cast4(w1s[i]); return; }
    i -= N4FC;
    if (i < N4CV) { w2d[i] = cast4(w2s[i]); return; }
    i -= N4CV;
    if (i < N4CLS) { w3d[i] = cast4(w3s[i]); return; }
    i -= N4CLS;
    if (i < NZ2) zp[i] = make_uint2(0, 0);
    return;
  }
  int hb = blockIdx.x - NFB;
  int tid = threadIdx.x;
  for (int i = tid; i < NB; i += 256) lh[i] = 0;
  __syncthreads();
  int base = hb * PEB;
#pragma unroll
  for (int i = 0; i < 32; ++i) {
    int e = base + i * 256 + tid;
    if (e < EE) atomicAdd(&lh[col[e] >> 9], 1);
  }
  __syncthreads();
  for (int i = tid; i < NB; i += 256) hist_mat[hb * NB + i] = lh[i];
}

// ---------------- k_pg0: partition (with self-bscan) ∪ layer-0 GEMM ----------------
__global__ __launch_bounds__(256) void k_pg0(const int* __restrict__ row, const int* __restrict__ col,
                                             const int* __restrict__ hist_mat, int* __restrict__ gfill,
                                             uint* __restrict__ pairbuf, int* __restrict__ bbase,
                                             const float* __restrict__ A, const ushort* __restrict__ W,
                                             const float* __restrict__ bias, ushort* __restrict__ Y,
                                             float* __restrict__ sums, int n) {
  __shared__ int smu[1024];
  int t = threadIdx.x;
  if (blockIdx.x < NPB) {
    int* lhist = smu;          // [196]
    int* lbase = smu + 196;    // [196]
    int* lgoff = smu + 392;    // [196]
    int* sm    = smu + 588;    // [256]
    int tot = 0;
    if (t < NB)
      for (int i = 0; i < NPB; ++i) tot += hist_mat[i * NB + t];
    sm[t] = tot;
    __syncthreads();
    for (int off = 1; off < 256; off <<= 1) {
      int v = (t >= off) ? sm[t - off] : 0;
      __syncthreads();
      sm[t] += v;
      __syncthreads();
    }
    if (t < NB) lbase[t] = sm[t] - tot;
    if (blockIdx.x == 0) {
      if (t < NB) bbase[t] = sm[t] - tot;
      if (t == NB - 1) bbase[NB] = sm[t];
    }
    for (int i = t; i < NB; i += 256) lhist[i] = 0;
    __syncthreads();
    int base = blockIdx.x * PEB;
    int packed[32];
#pragma unroll
    for (int i = 0; i < 32; ++i) {
      int e = base + i * 256 + t;
      packed[i] = -1;
      if (e < EE) {
        int c = col[e];
        int b = c >> 9, loc = c & 511;
        int p = atomicAdd(&lhist[b], 1);
        packed[i] = (b << 22) | (loc << 13) | p;
      }
    }
    __syncthreads();
    for (int i = t; i < NB; i += 256) lgoff[i] = atomicAdd(&gfill[i], lhist[i]);
    __syncthreads();
#pragma unroll
    for (int i = 0; i < 32; ++i) {
      if (packed[i] >= 0) {
        int e = base + i * 256 + t;
        int b = packed[i] >> 22, loc = (packed[i] >> 13) & 511, p = packed[i] & 8191;
        pairbuf[(size_t)lbase[b] + lgoff[b] + p] = ((uint)loc << 17) | (uint)row[e];
      }
    }
    return;
  }
  // ---------- layer-0 GEMM block (fp32 A, direct fragments) ----------
  float* ls1 = (float*)smu;        // [4][128]
  float* ls2 = (float*)smu + 512;
  int bid = blockIdx.x - NPB;
  int w = t >> 6, l = t & 63;
  int quad = l >> 4, m = l & 15;
  int r0 = bid * 128;
  bf16x8 af[2][4];
#pragma unroll
  for (int rt = 0; rt < 2; ++rt) {
    int ar = min(r0 + w * 32 + rt * 16 + m, n - 1);
#pragma unroll
    for (int ks = 0; ks < 4; ++ks)
      af[rt][ks] = frag_f32(A + (size_t)ar * 128 + ks * 32 + quad * 8);
  }
#pragma unroll
  for (int ct = 0; ct < 8; ++ct) {
    int c = ct * 16 + m;
    bf16x8 bfr[4];
#pragma unroll
    for (int ks = 0; ks < 4; ++ks)
      bfr[ks] = *(const bf16x8*)&W[(size_t)c * 128 + ks * 32 + quad * 8];
    float b = bias[c];
    float s1 = 0.f, s2 = 0.f;
#pragma unroll
    for (int rt = 0; rt < 2; ++rt) {
      f32x4 acc = {0.f, 0.f, 0.f, 0.f};
#pragma unroll
      for (int ks = 0; ks < 4; ++ks)
        acc = __builtin_amdgcn_mfma_f32_16x16x32_bf16(af[rt][ks], bfr[ks], acc, 0, 0, 0);
      int rbase = r0 + w * 32 + rt * 16 + quad * 4;
#pragma unroll
      for (int i2 = 0; i2 < 4; ++i2) {
        int r = rbase + i2;
        if (r < n) {
          float v = acc[i2] + b;
          s1 += v;
          s2 += v * v;
          Y[(size_t)r * 128 + c] = f2b(v);
        }
      }
    }
    s1 += __shfl_xor(s1, 16);
    s1 += __shfl_xor(s1, 32);
    s2 += __shfl_xor(s2, 16);
    s2 += __shfl_xor(s2, 32);
    if (quad == 0) {
      ls1[w * 128 + c] = s1;
      ls2[w * 128 + c] = s2;
    }
  }
  __syncthreads();
  if (t < 128) {
    float a1 = ls1[t] + ls1[128 + t] + ls1[256 + t] + ls1[384 + t];
    float a2 = ls2[t] + ls2[128 + t] + ls2[256 + t] + ls2[384 + t];
    atomicAdd(&sums[t], a1);
    atomicAdd(&sums[128 + t], a2);
  }
}

// ---------------- BN helpers ----------------
__device__ __forceinline__ void bn_prologue(float* ssl, const float* __restrict__ sums,
                                            const float* __restrict__ gamma,
                                            const float* __restrict__ beta) {
  int t = threadIdx.x;
  if (t < 128) {
    float mu = sums[t] * (1.f / NN);
    float var = sums[128 + t] * (1.f / NN) - mu * mu;
    float sc = gamma[t] * rsqrtf(var + BN_EPS);
    ssl[t] = sc;
    ssl[128 + t] = beta[t] - mu * sc;
  }
  __syncthreads();
}

__device__ __forceinline__ uint2 bn_elem(uint2 u, float4 sc, float4 sh) {
  float o0 = fmaxf(fmaf(sc.x, b2f(u.x & 0xffffu), sh.x), 0.f);
  float o1 = fmaxf(fmaf(sc.y, b2f(u.x >> 16), sh.y), 0.f);
  float o2 = fmaxf(fmaf(sc.z, b2f(u.y & 0xffffu), sh.z), 0.f);
  float o3 = fmaxf(fmaf(sc.w, b2f(u.y >> 16), sh.w), 0.f);
  uint2 o;
  o.x = (uint)f2b(o0) | ((uint)f2b(o1) << 16);
  o.y = (uint)f2b(o2) | ((uint)f2b(o3) << 16);
  return o;
}

__device__ __forceinline__ uint2 bn_elem_res(uint2 u, uint2 r, float4 sc, float4 sh) {
  float o0 = fmaxf(fmaf(sc.x, b2f(u.x & 0xffffu), sh.x), 0.f) + b2f(r.x & 0xffffu);
  float o1 = fmaxf(fmaf(sc.y, b2f(u.x >> 16), sh.y), 0.f) + b2f(r.x >> 16);
  float o2 = fmaxf(fmaf(sc.z, b2f(u.y & 0xffffu), sh.z), 0.f) + b2f(r.y & 0xffffu);
  float o3 = fmaxf(fmaf(sc.w, b2f(u.y >> 16), sh.w), 0.f) + b2f(r.y >> 16);
  uint2 o;
  o.x = (uint)f2b(o0) | ((uint)f2b(o1) << 16);
  o.y = (uint)f2b(o2) | ((uint)f2b(o3) << 16);
  return o;
}

// ---------------- k_mid: place (deg+scan+rowptr+dinv+srcbuf per bucket) ∪ bnapply layer-0 ----------------
__global__ __launch_bounds__(256) void k_mid(const uint* __restrict__ pairbuf,
                                             const int* __restrict__ bbase,
                                             int* __restrict__ rowptr, float* __restrict__ dinv,
                                             int* __restrict__ srcbuf,
                                             const uint2* __restrict__ y, uint2* __restrict__ h,
                                             uint2* __restrict__ x0, const float* __restrict__ sums,
                                             const float* __restrict__ gamma,
                                             const float* __restrict__ beta) {
  __shared__ __align__(16) int smraw[13569];  // stage[12288] | dega[512] | lrp[513] | ssum[256]
  if (blockIdx.x < NB) {
    int* stage = smraw;
    int* dega = smraw + 12288;
    int* lrp = smraw + 12800;
    int* ssum = smraw + 13313;
    int tid = threadIdx.x;
    int b = blockIdx.x;
    int nstart = b << 9;
    int nloc = min(nstart + 512, NN) - nstart;
    int estart = bbase[b];
    int count = bbase[b + 1] - estart;
    dega[tid] = 0;
    dega[256 + tid] = 0;
    __syncthreads();
    for (int i = tid; i < count; i += 256) atomicAdd(&dega[pairbuf[(size_t)estart + i] >> 17], 1);
    __syncthreads();
    int d0 = dega[2 * tid], d1 = dega[2 * tid + 1];
    ssum[tid] = d0 + d1;
    __syncthreads();
    for (int off = 1; off < 256; off <<= 1) {
      int t2 = (tid >= off) ? ssum[tid - off] : 0;
      __syncthreads();
      ssum[tid] += t2;
      __syncthreads();
    }
    int incl = ssum[tid];
    int ex = incl - (d0 + d1);
    lrp[2 * tid] = ex;
    lrp[2 * tid + 1] = ex + d0;
    if (tid == 255) lrp[512] = incl;
    __syncthreads();
    for (int i = tid; i < nloc; i += 256) {
      rowptr[nstart + i] = estart + lrp[i];
      int dg = dega[i];
      dinv[nstart + i] = (dg > 0) ? rsqrtf((float)dg) : 0.f;
    }
    if (b == NB - 1 && tid == 0) rowptr[NN] = estart + count;
    __syncthreads();
    dega[tid] = 0;
    dega[256 + tid] = 0;
    __syncthreads();
    if (count <= 12288) {
      for (int i = tid; i < count; i += 256) {
        uint v = pairbuf[(size_t)estart + i];
        int loc = v >> 17;
        int p = atomicAdd(&dega[loc], 1);
        stage[lrp[loc] + p] = (int)(v & 0x1FFFFu);
      }
      __syncthreads();
      for (int i = tid; i < count; i += 256) srcbuf[estart + i] = stage[i];
    } else {
      for (int i = tid; i < count; i += 256) {
        uint v = pairbuf[(size_t)estart + i];
        int loc = v >> 17;
        int p = atomicAdd(&dega[loc], 1);
        srcbuf[estart + lrp[loc] + p] = (int)(v & 0x1FFFFu);
      }
    }
    return;
  }
  float* ssl = (float*)smraw;
  bn_prologue(ssl, sums, gamma, beta);
  const float4* ss4 = (const float4*)ssl;
  for (int i = (blockIdx.x - NB) * 256 + threadIdx.x; i < NN * 32; i += ABB * 256) {
    int j = i & 31;
    uint2 o = bn_elem(y[i], ss4[j], ss4[32 + j]);
    h[i] = o;
    x0[i] = o;
  }
}

// ---------------- bnapply (layers 1..2): h = relu(bn(y)) + x0 ----------------
__global__ __launch_bounds__(256) void k_bnapply(const uint2* __restrict__ y, uint2* __restrict__ h,
                                                 const uint2* __restrict__ res,
                                                 const float* __restrict__ sums,
                                                 const float* __restrict__ gamma,
                                                 const float* __restrict__ beta) {
  __shared__ __align__(16) float ssl[256];
  bn_prologue(ssl, sums, gamma, beta);
  const float4* ss4 = (const float4*)ssl;
  for (int i = blockIdx.x * 256 + threadIdx.x; i < NN * 32; i += ABB * 256) {
    int j = i & 31;
    h[i] = bn_elem_res(y[i], res[i], ss4[j], ss4[32 + j]);
  }
}

// ---------------- SPMM (split, round-9 form): 16 gathers in flight per wave ----------------
__device__ __forceinline__ void fmac8(float* acc, uint4 v, float wgt) {
  acc[0] = fmaf(wgt, b2f(v.x & 0xffffu), acc[0]);
  acc[1] = fmaf(wgt, b2f(v.x >> 16), acc[1]);
  acc[2] = fmaf(wgt, b2f(v.y & 0xffffu), acc[2]);
  acc[3] = fmaf(wgt, b2f(v.y >> 16), acc[3]);
  acc[4] = fmaf(wgt, b2f(v.z & 0xffffu), acc[4]);
  acc[5] = fmaf(wgt, b2f(v.z >> 16), acc[5]);
  acc[6] = fmaf(wgt, b2f(v.w & 0xffffu), acc[6]);
  acc[7] = fmaf(wgt, b2f(v.w >> 16), acc[7]);
}

__global__ __launch_bounds__(256) void k_spmm(const uint4* __restrict__ h4, uint4* __restrict__ agg4,
                                              const int* __restrict__ rowptr,
                                              const int* __restrict__ srcbuf,
                                              const float* __restrict__ dinv) {
  int gid = blockIdx.x * 256 + threadIdx.x;
  int node = gid >> 6;
  if (node >= NN) return;
  int lane = threadIdx.x & 63;
  int g = lane >> 4, li = lane & 15;
  int e0 = rowptr[node], e1 = rowptr[node + 1];
  float acc[8];
#pragma unroll
  for (int j = 0; j < 8; ++j) acc[j] = 0.f;

  int eA = e0 + g;
  int s0 = (eA < e1) ? srcbuf[eA] : -1;
  int s1 = (eA + 4 < e1) ? srcbuf[eA + 4] : -1;
  int s2 = (eA + 8 < e1) ? srcbuf[eA + 8] : -1;
  int s3 = (eA + 12 < e1) ? srcbuf[eA + 12] : -1;
  while (eA < e1) {
    int eN = eA + 16;
    int t0 = (eN < e1) ? srcbuf[eN] : -1;
    int t1 = (eN + 4 < e1) ? srcbuf[eN + 4] : -1;
    int t2 = (eN + 8 < e1) ? srcbuf[eN + 8] : -1;
    int t3 = (eN + 12 < e1) ? srcbuf[eN + 12] : -1;
    int a1 = (s1 >= 0) ? s1 : s0;
    int a2 = (s2 >= 0) ? s2 : s0;
    int a3 = (s3 >= 0) ? s3 : s0;
    float w0 = dinv[s0];
    uint4 v0 = h4[(size_t)s0 * 16 + li];
    float w1 = (s1 >= 0) ? dinv[a1] : 0.f;
    uint4 v1 = h4[(size_t)a1 * 16 + li];
    float w2 = (s2 >= 0) ? dinv[a2] : 0.f;
    uint4 v2 = h4[(size_t)a2 * 16 + li];
    float w3 = (s3 >= 0) ? dinv[a3] : 0.f;
    uint4 v3 = h4[(size_t)a3 * 16 + li];
    fmac8(acc, v0, w0);
    fmac8(acc, v1, w1);
    fmac8(acc, v2, w2);
    fmac8(acc, v3, w3);
    s0 = t0; s1 = t1; s2 = t2; s3 = t3;
    eA = eN;
  }
#pragma unroll
  for (int j = 0; j < 8; ++j) {
    acc[j] += __shfl_xor(acc[j], 16);
    acc[j] += __shfl_xor(acc[j], 32);
  }
  if (g == 0) {
    float dc = dinv[node];
    uint4 o;
    o.x = (uint)f2b(acc[0] * dc) | ((uint)f2b(acc[1] * dc) << 16);
    o.y = (uint)f2b(acc[2] * dc) | ((uint)f2b(acc[3] * dc) << 16);
    o.z = (uint)f2b(acc[4] * dc) | ((uint)f2b(acc[5] * dc) << 16);
    o.w = (uint)f2b(acc[6] * dc) | ((uint)f2b(acc[7] * dc) << 16);
    agg4[(size_t)node * 16 + li] = o;
  }
}

// ---------------- MFMA GEMM, direct-fragment (bf16 A): Y = A @ W^T + b, + BN stats ----------------
__global__ __launch_bounds__(256) void k_mgemm(const ushort* __restrict__ A,
                                               const ushort* __restrict__ W,
                                               const float* __restrict__ bias,
                                               ushort* __restrict__ Y,
                                               float* __restrict__ sums, int n) {
  __shared__ float ls1[4][128];
  __shared__ float ls2[4][128];
  int t = threadIdx.x;
  int w = t >> 6, l = t & 63;
  int quad = l >> 4, m = l & 15;
  int r0 = blockIdx.x * 128;
  bf16x8 af[2][4];
#pragma unroll
  for (int rt = 0; rt < 2; ++rt) {
    int ar = min(r0 + w * 32 + rt * 16 + m, n - 1);
#pragma unroll
    for (int ks = 0; ks < 4; ++ks)
      af[rt][ks] = *(const bf16x8*)(A + (size_t)ar * 128 + ks * 32 + quad * 8);
  }
#pragma unroll
  for (int ct = 0; ct < 8; ++ct) {
    int c = ct * 16 + m;
    bf16x8 bfr[4];
#pragma unroll
    for (int ks = 0; ks < 4; ++ks)
      bfr[ks] = *(const bf16x8*)&W[(size_t)c * 128 + ks * 32 + quad * 8];
    float b = bias[c];
    float s1 = 0.f, s2 = 0.f;
#pragma unroll
    for (int rt = 0; rt < 2; ++rt) {
      f32x4 acc = {0.f, 0.f, 0.f, 0.f};
#pragma unroll
      for (int ks = 0; ks < 4; ++ks)
        acc = __builtin_amdgcn_mfma_f32_16x16x32_bf16(af[rt][ks], bfr[ks], acc, 0, 0, 0);
      int rbase = r0 + w * 32 + rt * 16 + quad * 4;
#pragma unroll
      for (int i2 = 0; i2 < 4; ++i2) {
        int r = rbase + i2;
        if (r < n) {
          float v = acc[i2] + b;
          s1 += v;
          s2 += v * v;
          Y[(size_t)r * 128 + c] = f2b(v);
        }
      }
    }
    s1 += __shfl_xor(s1, 16);
    s1 += __shfl_xor(s1, 32);
    s2 += __shfl_xor(s2, 16);
    s2 += __shfl_xor(s2, 32);
    if (quad == 0) {
      ls1[w][c] = s1;
      ls2[w][c] = s2;
    }
  }
  __syncthreads();
  if (t < 128) {
    float a1 = ls1[0][t] + ls1[1][t] + ls1[2][t] + ls1[3][t];
    float a2 = ls2[0][t] + ls2[1][t] + ls2[2][t] + ls2[3][t];
    atomicAdd(&sums[t], a1);
    atomicAdd(&sums[128 + t], a2);
  }
}

// ---------------- fused bnapply layer-3 + classifier: h3 never materialized ----------------
__global__ __launch_bounds__(256) void k_bncls(const uint2* __restrict__ y, const uint2* __restrict__ x0,
                                               const float* __restrict__ sums,
                                               const float* __restrict__ gamma,
                                               const float* __restrict__ beta,
                                               const ushort* __restrict__ W,
                                               const float* __restrict__ bias,
                                               float* __restrict__ out, int n) {
  __shared__ ushort As[64][136];
  __shared__ __align__(16) float ssl[256];
  bn_prologue(ssl, sums, gamma, beta);
  const float4* ss4 = (const float4*)ssl;
  int t = threadIdx.x;
  int r0 = blockIdx.x * 64;
  for (int idx = t; idx < 64 * 32; idx += 256) {
    int r = idx >> 5, c2 = idx & 31;
    int gr = r0 + r;
    uint2 o = make_uint2(0, 0);
    if (gr < n)
      o = bn_elem_res(y[(size_t)gr * 32 + c2], x0[(size_t)gr * 32 + c2], ss4[c2], ss4[32 + c2]);
    *(uint2*)&As[r][c2 * 4] = o;
  }
  __syncthreads();
  int w = t >> 6, l = t & 63;
  int quad = l >> 4, m = l & 15;
  bf16x8 af[4];
#pragma unroll
  for (int ks = 0; ks < 4; ++ks)
    af[ks] = *(const bf16x8*)&As[w * 16 + m][ks * 32 + quad * 8];
#pragma unroll
  for (int ct = 0; ct < 3; ++ct) {
    int c = ct * 16 + m;
    int wr = min(c, DOUT - 1);
    bf16x8 bfr[4];
#pragma unroll
    for (int ks = 0; ks < 4; ++ks)
      bfr[ks] = *(const bf16x8*)&W[(size_t)wr * 128 + ks * 32 + quad * 8];
    f32x4 acc = {0.f, 0.f, 0.f, 0.f};
#pragma unroll
    for (int ks = 0; ks < 4; ++ks)
      acc = __builtin_amdgcn_mfma_f32_16x16x32_bf16(af[ks], bfr[ks], acc, 0, 0, 0);
    if (c < DOUT) {
      float b = bias[c];
      int rbase = r0 + w * 16 + quad * 4;
#pragma unroll
      for (int i = 0; i < 4; ++i) {
        int r = rbase + i;
        if (r < n) out[(size_t)r * DOUT + c] = acc[i] + b;
      }
    }
  }
}

// ---------------- launch ----------------
extern "C" void kernel_launch(void* const* d_in, const int* in_sizes, int n_in,
                              void* d_out, int out_size, void* d_ws, size_t ws_size,
                              hipStream_t stream) {
  const float* x      = (const float*)d_in[0];
  const int*   ei     = (const int*)d_in[1];
  const float* fc_w   = (const float*)d_in[2];
  const float* fc_b   = (const float*)d_in[3];
  const float* conv_w = (const float*)d_in[4];
  const float* conv_b = (const float*)d_in[5];
  const float* bn_g   = (const float*)d_in[6];
  const float* bn_b   = (const float*)d_in[7];
  const float* cls_w  = (const float*)d_in[8];
  const float* cls_b  = (const float*)d_in[9];
  const int* row  = ei;       // edge_index[0]
  const int* colv = ei + EE;  // edge_index[1]

  char* w = (char*)d_ws;
  auto alloc = [&](size_t bytes) {
    char* p = w;
    w += (bytes + 255) & ~(size_t)255;
    return p;
  };
  ushort* hb     = (ushort*)alloc((size_t)NN * 128 * 2);
  ushort* x0b    = (ushort*)alloc((size_t)NN * 128 * 2);
  ushort* aggb   = (ushort*)alloc((size_t)NN * 128 * 2);
  ushort* yb     = (ushort*)alloc((size_t)NN * 128 * 2);
  ushort* wb_fc  = (ushort*)alloc(128 * 128 * 2);
  ushort* wb_cv  = (ushort*)alloc(3 * 128 * 128 * 2);
  ushort* wb_cls = (ushort*)alloc(DOUT * 128 * 2);
  int*   srcbuf  = (int*)alloc((size_t)EE * 4);
  uint*  pairbuf = (uint*)alloc((size_t)EE * 4);
  int*   hist_mat = (int*)alloc((size_t)NPB * NB * 4);
  int*   bbase   = (int*)alloc((NB + 1) * 4);
  int*   rowptr  = (int*)alloc((size_t)(NN + 1) * 4);
  float* dinv    = (float*)alloc((size_t)NN * 4);
  // contiguous zero region: sums(1024 floats) | gfill(196 ints)
  float* sums   = (float*)alloc(1024 * 4 + 196 * 4);
  int*   gfill  = (int*)(sums + 1024);

  // 1. front: weight casts + zeros + per-block bucket histograms
  k_front<<<NFB + NPB, 256, 0, stream>>>(
      (const float4*)fc_w, (uint2*)wb_fc, (const float4*)conv_w, (uint2*)wb_cv,
      (const float4*)cls_w, (uint2*)wb_cls, (uint2*)sums, colv, hist_mat);
  // 2. partition (self-bscan) ∪ layer-0 GEMM
  k_pg0<<<NPB + (NN + 127) / 128, 256, 0, stream>>>(row, colv, hist_mat, gfill, pairbuf, bbase,
                                                    x, wb_fc, fc_b, yb, sums + 0 * 256, NN);
  // 3. place ∪ bnapply0
  k_mid<<<NB + ABB, 256, 0, stream>>>(pairbuf, bbase, rowptr, dinv, srcbuf,
                                      (const uint2*)yb, (uint2*)hb, (uint2*)x0b,
                                      sums + 0 * 256, bn_g, bn_b);
  // conv layers: split spmm + gemm; bnapply for layers 0..1, fused bn+cls after layer 2
  for (int i = 0; i < 3; ++i) {
    k_spmm<<<(NN * 64 + 255) / 256, 256, 0, stream>>>((const uint4*)hb, (uint4*)aggb, rowptr, srcbuf, dinv);
    k_mgemm<<<(NN + 127) / 128, 256, 0, stream>>>(aggb, wb_cv + (size_t)i * 128 * 128,
                                                  conv_b + (size_t)i * 128, yb,
                                                  sums + (size_t)(i + 1) * 256, NN);
    if (i < 2)
      k_bnapply<<<ABB, 256, 0, stream>>>((const uint2*)yb, (uint2*)hb, (const uint2*)x0b,
                                         sums + (size_t)(i + 1) * 256,
                                         bn_g + (size_t)(i + 1) * 128, bn_b + (size_t)(i + 1) * 128);
  }
  // final: bnapply3 ∪ classifier
  k_bncls<<<G64, 256, 0, stream>>>((const uint2*)yb, (const uint2*)x0b, sums + 3 * 256,
                                   bn_g + 3 * 128, bn_b + 3 * 128, wb_cls, cls_b, (float*)d_out, NN);
}